// Round 13
// baseline (878.878 us; speedup 1.0000x reference)
//
#include <hip/hip_runtime.h>
#include <stdint.h>

#define N_NODES 20000
#define E_EDGES 640000
#define IN_DIM  128
#define HID     256
#define MAXW    512
#define HEADS   32
#define BN_EPS  1e-5f
#define NT      20480
#define NB_SCAN 79

typedef __attribute__((ext_vector_type(8))) short bf16x8;
typedef __attribute__((ext_vector_type(4))) float f32x4;
typedef __attribute__((ext_vector_type(16))) float f32x16;
typedef unsigned short ushort_t;

static __device__ __forceinline__ float bf2f(ushort_t u){
  union { unsigned int i; float f; } v; v.i = ((unsigned int)u) << 16; return v.f;
}
static __device__ __forceinline__ ushort_t f2bf(float f){
  union { float f; unsigned int i; } v; v.f = f;
  unsigned int r = v.i + 0x7fffu + ((v.i >> 16) & 1u);
  return (ushort_t)(r >> 16);
}

// ---------------- K0: init (zero G, s, deg, hT tail) + int64 layout detect ----------------
__global__ void k_initdet(const int* __restrict__ ei, float* __restrict__ G,
                          float* __restrict__ s, int* __restrict__ deg,
                          int* __restrict__ flag, ushort_t* __restrict__ hT){
  int i = blockIdx.x * blockDim.x + threadIdx.x;
  int stride = gridDim.x * blockDim.x;
  float4 z4 = make_float4(0.f, 0.f, 0.f, 0.f);
  float4* Gd = (float4*)G;
  for (int j = i; j < 256 * 256 / 4; j += stride) Gd[j] = z4;
  for (int j = i; j < N_NODES; j += stride) deg[j] = 0;
  if (i < 256) s[i] = 0.f;
  // zero hT pad columns [20000, 20480) for all 256 rows: 256*60 uint4
  uint4 zi = make_uint4(0u, 0u, 0u, 0u);
  for (int j = i; j < 256 * 60; j += stride){
    int c = j / 60, o = (j % 60) * 8;
    *(uint4*)(hT + (size_t)c * NT + N_NODES + o) = zi;
  }
  if (blockIdx.x == 0){
    __shared__ int any_nz;
    if (threadIdx.x == 0) any_nz = 0;
    __syncthreads();
    int nz = 0;
    for (int k = threadIdx.x; k < 4096; k += blockDim.x)
      if (ei[2 * k + 1] != 0) nz = 1;
    if (nz) atomicOr(&any_nz, 1);
    __syncthreads();
    if (threadIdx.x == 0) flag[0] = (any_nz == 0) ? 1 : 0;   // 1 => int64 layout
  }
}

// ---------------- CSR build: histogram ----------------
__global__ __launch_bounds__(256) void k_hist(const int* __restrict__ ei,
                                              const int* __restrict__ flag,
                                              int* __restrict__ deg){
  int e = blockIdx.x * 256 + threadIdx.x;
  if (e >= E_EDGES) return;
  int src, dst;
  if (flag[0]){ src = ei[2 * e]; dst = ei[2 * E_EDGES + 2 * e]; }
  else        { src = ei[e];     dst = ei[E_EDGES + e]; }
  if ((unsigned)src >= N_NODES || (unsigned)dst >= N_NODES) return;
  atomicAdd(&deg[dst], 1);
}

// ---------------- parallel scan stage 1: per-block sums ----------------
__global__ __launch_bounds__(256) void k_scan1(const int* __restrict__ deg,
                                               int* __restrict__ bsum){
  __shared__ int ws[4];
  int b = blockIdx.x, t = threadIdx.x, i = b * 256 + t;
  int v = (i < N_NODES) ? deg[i] : 0;
  #pragma unroll
  for (int o = 32; o; o >>= 1) v += __shfl_down(v, o);
  if ((t & 63) == 0) ws[t >> 6] = v;
  __syncthreads();
  if (t == 0) bsum[b] = ws[0] + ws[1] + ws[2] + ws[3];
}

// ---------------- scan stage 2+3 fused: block-level exclusive scan ----------------
__global__ __launch_bounds__(256) void k_scan3(const int* __restrict__ deg,
                                               const int* __restrict__ bsum,
                                               int* __restrict__ start,
                                               int* __restrict__ cursor){
  __shared__ int a[2][256];
  __shared__ int base;
  int b = blockIdx.x, t = threadIdx.x, i = b * 256 + t;
  if (t == 0){
    int r = 0;
    for (int k = 0; k < b; k++) r += bsum[k];
    base = r;
  }
  int v = (i < N_NODES) ? deg[i] : 0;
  a[0][t] = v;
  __syncthreads();
  int pb = 0;
  for (int o = 1; o < 256; o <<= 1){
    int x = a[pb][t] + ((t >= o) ? a[pb][t - o] : 0);
    a[pb ^ 1][t] = x;
    __syncthreads();
    pb ^= 1;
  }
  if (i < N_NODES){
    int ex = base + a[pb][t] - v;
    start[i] = ex; cursor[i] = ex;
  }
}

// ---------------- CSR build: scatter edge sources ----------------
__global__ __launch_bounds__(256) void k_scatter(const int* __restrict__ ei,
                                                 const int* __restrict__ flag,
                                                 int* __restrict__ cursor,
                                                 int* __restrict__ eids){
  int e = blockIdx.x * 256 + threadIdx.x;
  if (e >= E_EDGES) return;
  int src, dst;
  if (flag[0]){ src = ei[2 * e]; dst = ei[2 * E_EDGES + 2 * e]; }
  else        { src = ei[e];     dst = ei[E_EDGES + e]; }
  if ((unsigned)src >= N_NODES || (unsigned)dst >= N_NODES) return;
  int p = atomicAdd(&cursor[dst], 1);
  eids[p] = src;
}

// ---------------- K-agg: agg[dst] = x[dst] + sum_{e in bucket} x[src_e] ----------------
__global__ __launch_bounds__(256) void k_agg(const float* __restrict__ x,
                                             const int* __restrict__ start,
                                             const int* __restrict__ deg,
                                             const int* __restrict__ eids,
                                             float* __restrict__ agg){
  int wid = (blockIdx.x * 256 + threadIdx.x) >> 6;
  int lane = threadIdx.x & 63;
  if (wid >= N_NODES) return;
  int s0 = start[wid], d = deg[wid];
  float2 acc = *(const float2*)(x + (size_t)wid * IN_DIM + 2 * lane);
  int i = 0;
  for (; i + 4 <= d; i += 4){
    int e0 = eids[s0+i], e1 = eids[s0+i+1], e2 = eids[s0+i+2], e3 = eids[s0+i+3];
    float2 v0 = *(const float2*)(x + (size_t)e0 * IN_DIM + 2 * lane);
    float2 v1 = *(const float2*)(x + (size_t)e1 * IN_DIM + 2 * lane);
    float2 v2 = *(const float2*)(x + (size_t)e2 * IN_DIM + 2 * lane);
    float2 v3 = *(const float2*)(x + (size_t)e3 * IN_DIM + 2 * lane);
    acc.x += (v0.x + v1.x) + (v2.x + v3.x);
    acc.y += (v0.y + v1.y) + (v2.y + v3.y);
  }
  for (; i < d; i++){
    int e0 = eids[s0+i];
    float2 v0 = *(const float2*)(x + (size_t)e0 * IN_DIM + 2 * lane);
    acc.x += v0.x; acc.y += v0.y;
  }
  *(float2*)(agg + (size_t)wid * IN_DIM + 2 * lane) = acc;
}

// ---------------- K2: h = relu(agg @ Wb + bb) -> hbf (row) + hT (col) + col-sums s ----------------
__global__ __launch_bounds__(256) void k_backbone(const float* __restrict__ agg,
                                                  const float* __restrict__ Wb,
                                                  const float* __restrict__ bb,
                                                  ushort_t* __restrict__ hbf,
                                                  ushort_t* __restrict__ hT,
                                                  float* __restrict__ s){
  __shared__ float WbS[32][256];
  __shared__ float aggS[32][36];
  int c = threadIdx.x;
  int n0 = blockIdx.x * 32;
  float acc[32];
  float bias = bb[c];
  #pragma unroll
  for (int i = 0; i < 32; i++) acc[i] = bias;
  for (int dc = 0; dc < 4; ++dc){
    __syncthreads();
    const float4* wsrc = (const float4*)(Wb + dc * 32 * 256);
    float4* wdst = (float4*)&WbS[0][0];
    #pragma unroll
    for (int i = 0; i < 8; i++) wdst[c + i * 256] = wsrc[c + i * 256];
    {
      int n = c >> 3, c4 = (c & 7) * 4;
      float4 v = *(const float4*)(agg + (size_t)(n0 + n) * IN_DIM + dc * 32 + c4);
      aggS[n][c4 + 0] = v.x; aggS[n][c4 + 1] = v.y;
      aggS[n][c4 + 2] = v.z; aggS[n][c4 + 3] = v.w;
    }
    __syncthreads();
    for (int d = 0; d < 32; ++d){
      float w = WbS[d][c];
      #pragma unroll
      for (int n = 0; n < 32; n++) acc[n] += aggS[n][d] * w;
    }
  }
  float ls = 0.f;
  ushort_t hrow[32];
  #pragma unroll
  for (int n = 0; n < 32; n++){
    float hv = acc[n] > 0.f ? acc[n] : 0.f;
    ushort_t hb = f2bf(hv);
    hbf[(size_t)(n0 + n) * HID + c] = hb;
    hrow[n] = hb;
    ls += bf2f(hb);
  }
  #pragma unroll
  for (int i = 0; i < 4; i++)
    *(uint4*)(hT + (size_t)c * NT + n0 + i * 8) = *(uint4*)(hrow + i * 8);
  unsafeAtomicAdd(&s[c], ls);
}

// ---------------- K-gram2: G += hT @ hT^T via 32x32x16 MFMA ----------------
__global__ __launch_bounds__(256) void k_gram2(const ushort_t* __restrict__ hT,
                                               float* __restrict__ G){
  const int t = threadIdx.x;
  const int w = t >> 6, l = t & 63;
  const int s = blockIdx.x, hh = blockIdx.y;
  const int wr = w >> 1, wc = w & 1;
  const int ca = hh * 128 + wr * 64;
  const int cb = wc * 128;
  const int l31 = l & 31, l5 = l >> 5;
  f32x16 acc[2][4];
  #pragma unroll
  for (int a = 0; a < 2; a++)
    #pragma unroll
    for (int b = 0; b < 4; b++)
      #pragma unroll
      for (int r = 0; r < 16; r++) acc[a][b][r] = 0.f;

  const size_t kb0 = (size_t)s * 512 + l5 * 8;
  for (int ks = 0; ks < 32; ks++){
    size_t k = kb0 + ks * 16;
    bf16x8 af[2], bfr[4];
    #pragma unroll
    for (int a = 0; a < 2; a++)
      af[a] = *(const bf16x8*)(hT + (size_t)(ca + a * 32 + l31) * NT + k);
    #pragma unroll
    for (int b = 0; b < 4; b++)
      bfr[b] = *(const bf16x8*)(hT + (size_t)(cb + b * 32 + l31) * NT + k);
    #pragma unroll
    for (int a = 0; a < 2; a++)
      #pragma unroll
      for (int b = 0; b < 4; b++)
        acc[a][b] = __builtin_amdgcn_mfma_f32_32x32x16_bf16(af[a], bfr[b], acc[a][b], 0, 0, 0);
  }
  #pragma unroll
  for (int a = 0; a < 2; a++)
    #pragma unroll
    for (int b = 0; b < 4; b++)
      #pragma unroll
      for (int r = 0; r < 16; r++){
        int grow = (r & 3) + 8 * (r >> 2) + 4 * l5;
        unsafeAtomicAdd(&G[(size_t)(ca + a * 32 + grow) * 256 + cb + b * 32 + l31], acc[a][b][r]);
      }
}

// ---------------- K5: transpose+convert, writing PRE-SWIZZLED LDS-image layouts ----------------
__global__ __launch_bounds__(256) void k_transpose(const float* __restrict__ W1,
                                                   const float* __restrict__ W2,
                                                   ushort_t* __restrict__ w1t,
                                                   ushort_t* __restrict__ w2t){
  __shared__ float tile[32][33];
  int which = blockIdx.z, h = blockIdx.y, b = blockIdx.x;
  const float* src; int R, C;
  if (which == 0){ src = W1 + (size_t)h * 256 * 512; R = 256; C = 512; }
  else           { src = W2 + (size_t)h * 512 * 256; R = 512; C = 256; }
  int tcn = C >> 5;
  int tr = b / tcn, tc = b % tcn;
  int r0 = tr * 32, c0 = tc * 32;
  int tx = threadIdx.x & 31, ty = threadIdx.x >> 5;
  #pragma unroll
  for (int i = 0; i < 32; i += 8) tile[ty + i][tx] = src[(size_t)(r0 + ty + i) * C + c0 + tx];
  __syncthreads();
  if (which == 0){
    ushort_t* dst = w1t + (size_t)h * 512 * 256;
    #pragma unroll
    for (int i = 0; i < 32; i += 8){
      int M = c0 + ty + i;
      int D = r0 + tx;
      int D2 = (((D >> 3) ^ (M & 7)) << 3) | (D & 7);
      dst[(size_t)M * 256 + D2] = f2bf(tile[tx][ty + i]);
    }
  } else {
    ushort_t* dst = w2t + (size_t)h * 256 * 512;
    #pragma unroll
    for (int i = 0; i < 32; i += 8){
      int dd = c0 + ty + i;
      int m  = r0 + tx;
      int g2 = ((m >> 3) & 3) ^ (dd & 3) ^ ((dd >> 2) & 3);
      size_t idx = (size_t)(m >> 5) * 8192 + dd * 32 + (g2 << 3) + (m & 7);
      dst[idx] = f2bf(tile[tx][ty + i]);
    }
  }
}

// ---------------- K4: BN stats (un-permutes w1t granules on load) ----------------
__global__ __launch_bounds__(256) void k_stats(const float* __restrict__ G,
                                               const float* __restrict__ s,
                                               const ushort_t* __restrict__ w1t,
                                               const float* __restrict__ b1,
                                               const float* __restrict__ gamma,
                                               const float* __restrict__ beta,
                                               float* __restrict__ As,
                                               float* __restrict__ Bs){
  __shared__ ushort_t wL[256][64];
  __shared__ float GL[16][256];
  __shared__ float sL[256];
  __shared__ float red[4][64];
  int h = blockIdx.y, m0 = blockIdx.x * 64;
  int t = threadIdx.x, m = t & 63, q = t >> 6;
  {
    int mm = t >> 2, part = t & 3;
    int Mrow = m0 + mm;
    const ushort_t* srcr = w1t + ((size_t)h * 512 + Mrow) * 256;
    #pragma unroll
    for (int k4 = 0; k4 < 16; ++k4){
      int kb = part * 64 + k4 * 4;
      int eo = (((kb >> 3) ^ (Mrow & 7)) << 3) | (kb & 7);
      ushort4 v = *(const ushort4*)(srcr + eo);
      wL[kb+0][mm]=v.x; wL[kb+1][mm]=v.y; wL[kb+2][mm]=v.z; wL[kb+3][mm]=v.w;
    }
  }
  sL[t & 255] = s[t & 255];
  float quad = 0.f;
  for (int dc = 0; dc < 16; ++dc){
    __syncthreads();
    const float4* gs = (const float4*)(G + (size_t)dc * 16 * 256);
    float4* gd = (float4*)&GL[0][0];
    #pragma unroll
    for (int i = 0; i < 4; i++) gd[t + i * 256] = gs[t + i * 256];
    __syncthreads();
    #pragma unroll
    for (int i = 0; i < 4; i++){
      int dl = q * 4 + i;
      float wd = bf2f(wL[dc * 16 + dl][m]);
      float u = 0.f;
      for (int k = 0; k < 256; ++k) u += GL[dl][k] * bf2f(wL[k][m]);
      quad += wd * u;
    }
  }
  red[q][m] = quad;
  __syncthreads();
  if (q == 0){
    float qd = red[0][m] + red[1][m] + red[2][m] + red[3][m];
    float dot_s = 0.f;
    for (int k = 0; k < 256; ++k) dot_s += sL[k] * bf2f(wL[k][m]);
    float b1v = b1[(size_t)h * 512 + m0 + m];
    float invN = 1.f / (float)N_NODES;
    float mean = dot_s * invN + b1v;
    float ez2 = (qd + 2.f * b1v * dot_s) * invN + b1v * b1v;
    float var = ez2 - mean * mean;
    float rstd = rsqrtf(var + BN_EPS);
    float gv = gamma[(size_t)h * 512 + m0 + m];
    float be = beta[(size_t)h * 512 + m0 + m];
    float Av = rstd * gv;
    As[(size_t)h * 512 + m0 + m] = Av;
    Bs[(size_t)h * 512 + m0 + m] = be - mean * Av;
  }
}

// ---------------- K6 v13: DMA staging (pre-swizzled) + wave-private asw handoff (no bpermute) ----------------
__global__ __launch_bounds__(512, 2) void k_main(const ushort_t* __restrict__ hbf,
                                                 const ushort_t* __restrict__ w1t,
                                                 const ushort_t* __restrict__ w2t,
                                                 const float* __restrict__ As,
                                                 const float* __restrict__ Bs,
                                                 const float* __restrict__ b2,
                                                 float* __restrict__ out){
  __shared__ __align__(16) char lds_all[81920];   // [0,64K): 2x(w1 16K|w2 16K); [64K,80K): 8x2KB asw
  const int h = blockIdx.y;
  const int n0 = blockIdx.x * 256;
  const int t = threadIdx.x;
  const int w = t >> 6, l = t & 63;
  const int l15 = l & 15, l4 = l >> 4;
  const int nw = n0 + w * 32;
  const f32x4 fzero = {0.f, 0.f, 0.f, 0.f};
  const bf16x8 bzero = {0,0,0,0,0,0,0,0};
  char* asw = lds_all + 65536 + w * 2048;   // wave-private 32 rows x 64B

  bf16x8 afr[2][8];
  #pragma unroll
  for (int nset = 0; nset < 2; nset++){
    int row = nw + nset * 16 + l15;
    const ushort_t* p = hbf + (size_t)row * HID + l4 * 8;
    #pragma unroll
    for (int kk = 0; kk < 8; kk++){
      bf16x8 v = bzero;
      if (row < N_NODES) v = *(const bf16x8*)(p + kk * 32);
      afr[nset][kk] = v;
    }
  }
  f32x4 oacc[16][2];
  #pragma unroll
  for (int i = 0; i < 16; i++){ oacc[i][0] = fzero; oacc[i][1] = fzero; }

  const float* Asp = As + (size_t)h * 512;
  const float* Bsp = Bs + (size_t)h * 512;
  const char* w1g = (const char*)(w1t + (size_t)h * 512 * 256);
  const char* w2g = (const char*)(w2t + (size_t)h * 256 * 512);
  const int woff = w * 2048 + l * 16;

  // prologue: DMA chunk 0 -> buffer 0
  {
    __builtin_amdgcn_global_load_lds((const __attribute__((address_space(1))) void*)(w1g + woff),
                                     (__attribute__((address_space(3))) void*)(lds_all + w * 2048), 16, 0, 0);
    __builtin_amdgcn_global_load_lds((const __attribute__((address_space(1))) void*)(w1g + woff + 1024),
                                     (__attribute__((address_space(3))) void*)(lds_all + w * 2048 + 1024), 16, 0, 0);
    __builtin_amdgcn_global_load_lds((const __attribute__((address_space(1))) void*)(w2g + woff),
                                     (__attribute__((address_space(3))) void*)(lds_all + 16384 + w * 2048), 16, 0, 0);
    __builtin_amdgcn_global_load_lds((const __attribute__((address_space(1))) void*)(w2g + woff + 1024),
                                     (__attribute__((address_space(3))) void*)(lds_all + 16384 + w * 2048 + 1024), 16, 0, 0);
  }
  __syncthreads();

  for (int c = 0; c < 16; ++c){
    const int cur = c & 1;
    const int mc0 = c * 32;
    const bool pf = (c < 15);
    if (pf){
      const int nb = (c + 1) * 16384;
      char* db = lds_all + (cur ^ 1) * 32768;
      __builtin_amdgcn_global_load_lds((const __attribute__((address_space(1))) void*)(w1g + nb + woff),
                                       (__attribute__((address_space(3))) void*)(db + w * 2048), 16, 0, 0);
      __builtin_amdgcn_global_load_lds((const __attribute__((address_space(1))) void*)(w1g + nb + woff + 1024),
                                       (__attribute__((address_space(3))) void*)(db + w * 2048 + 1024), 16, 0, 0);
      __builtin_amdgcn_global_load_lds((const __attribute__((address_space(1))) void*)(w2g + nb + woff),
                                       (__attribute__((address_space(3))) void*)(db + 16384 + w * 2048), 16, 0, 0);
      __builtin_amdgcn_global_load_lds((const __attribute__((address_space(1))) void*)(w2g + nb + woff + 1024),
                                       (__attribute__((address_space(3))) void*)(db + 16384 + w * 2048 + 1024), 16, 0, 0);
    }
    const char* w1b = lds_all + cur * 32768;
    const char* w2b = lds_all + cur * 32768 + 16384;

    // ---- GEMM1 (swapped): zt[nset][ct]
    f32x4 zt[2][2];
    zt[0][0] = fzero; zt[0][1] = fzero; zt[1][0] = fzero; zt[1][1] = fzero;
    __builtin_amdgcn_s_setprio(1);
    #pragma unroll
    for (int kk = 0; kk < 8; kk++){
      #pragma unroll
      for (int ct = 0; ct < 2; ct++){
        int r1 = ct * 16 + l15;
        int gr = kk * 4 + l4;
        bf16x8 wf = *(const bf16x8*)(w1b + r1 * 512 + ((gr ^ (r1 & 7)) * 16));
        zt[0][ct] = __builtin_amdgcn_mfma_f32_16x16x32_bf16(wf, afr[0][kk], zt[0][ct], 0, 0, 0);
        zt[1][ct] = __builtin_amdgcn_mfma_f32_16x16x32_bf16(wf, afr[1][kk], zt[1][ct], 0, 0, 0);
      }
    }
    __builtin_amdgcn_s_setprio(0);

    // ---- BN fold + ReLU + pack -> wave-private asw (m-linear 64B rows)
    #pragma unroll
    for (int ct = 0; ct < 2; ct++){
      int mb = mc0 + ct * 16 + l4 * 4;
      float4 Av = *(const float4*)(Asp + mb);
      float4 Bv = *(const float4*)(Bsp + mb);
      #pragma unroll
      for (int nset = 0; nset < 2; nset++){
        float a0 = zt[nset][ct][0] * Av.x + Bv.x; a0 = a0 > 0.f ? a0 : 0.f;
        float a1 = zt[nset][ct][1] * Av.y + Bv.y; a1 = a1 > 0.f ? a1 : 0.f;
        float a2 = zt[nset][ct][2] * Av.z + Bv.z; a2 = a2 > 0.f ? a2 : 0.f;
        float a3 = zt[nset][ct][3] * Av.w + Bv.w; a3 = a3 > 0.f ? a3 : 0.f;
        uint2 pk;
        pk.x = (unsigned)f2bf(a0) | ((unsigned)f2bf(a1) << 16);
        pk.y = (unsigned)f2bf(a2) | ((unsigned)f2bf(a3) << 16);
        *(uint2*)(asw + (nset * 16 + l15) * 64 + ct * 32 + l4 * 8) = pk;
      }
    }
    // ---- read back as GEMM2 B-frags (wave-local ordering via lgkmcnt)
    bf16x8 aa[2];
    aa[0] = *(const bf16x8*)(asw + l15 * 64 + l4 * 16);
    aa[1] = *(const bf16x8*)(asw + (16 + l15) * 64 + l4 * 16);

    // ---- GEMM2 (swapped)
    __builtin_amdgcn_s_setprio(1);
    #pragma unroll
    for (int ddt = 0; ddt < 16; ddt++){
      int dd = ddt * 16 + l15;
      int g2 = l4 ^ (dd & 3) ^ ((dd >> 2) & 3);
      bf16x8 wf2 = *(const bf16x8*)(w2b + dd * 64 + g2 * 16);
      oacc[ddt][0] = __builtin_amdgcn_mfma_f32_16x16x32_bf16(wf2, aa[0], oacc[ddt][0], 0, 0, 0);
      oacc[ddt][1] = __builtin_amdgcn_mfma_f32_16x16x32_bf16(wf2, aa[1], oacc[ddt][1], 0, 0, 0);
    }
    __builtin_amdgcn_s_setprio(0);

    __syncthreads();   // drains DMA (vmcnt) + orders buffer reuse
  }

  // ---- epilogue: per-wave 8KB LDS slice, transpose to coalesced 512B row stores
  char* slice = lds_all + w * 8192;
  const int gsl = l & 31;
  const int rhalf = l >> 5;
  #pragma unroll
  for (int nset = 0; nset < 2; nset++){
    #pragma unroll
    for (int half = 0; half < 2; half++){
      #pragma unroll
      for (int dq = 0; dq < 8; dq++){
        int ddt = half * 8 + dq;
        *(f32x4*)(slice + l15 * 512 + (((dq * 4 + l4) ^ (l15 & 7)) * 16)) = oacc[ddt][nset];
      }
      float4 b2v = *(const float4*)(b2 + (size_t)h * 256 + half * 128 + gsl * 4);
      #pragma unroll
      for (int j = 0; j < 8; j++){
        int rr = rhalf + j * 2;
        f32x4 v = *(const f32x4*)(slice + rr * 512 + ((gsl ^ (rr & 7)) * 16));
        int n = nw + nset * 16 + rr;
        if (n < N_NODES){
          float4 o;
          o.x = v[0] + b2v.x; o.y = v[1] + b2v.y;
          o.z = v[2] + b2v.z; o.w = v[3] + b2v.w;
          *(float4*)(out + (size_t)n * (HEADS * HID) + h * HID + half * 128 + gsl * 4) = o;
        }
      }
      __syncthreads();
    }
  }
}

extern "C" void kernel_launch(void* const* d_in, const int* in_sizes, int n_in,
                              void* d_out, int out_size, void* d_ws, size_t ws_size,
                              hipStream_t stream){
  const float* x     = (const float*)d_in[0];
  const int*   ei    = (const int*)  d_in[1];
  const float* Wb    = (const float*)d_in[2];
  const float* bb    = (const float*)d_in[3];
  const float* W1    = (const float*)d_in[4];
  const float* b1    = (const float*)d_in[5];
  const float* gamma = (const float*)d_in[6];
  const float* beta  = (const float*)d_in[7];
  const float* W2    = (const float*)d_in[8];
  const float* b2    = (const float*)d_in[9];
  float* out = (float*)d_out;

  char* ws = (char*)d_ws;
  size_t off = 0;
  auto alloc = [&](size_t bytes){ void* p = ws + off; off += (bytes + 255) & ~(size_t)255; return p; };
  float*    agg  = (float*)   alloc((size_t)N_NODES * IN_DIM * 4);
  ushort_t* hbf  = (ushort_t*)alloc((size_t)N_NODES * HID * 2);
  ushort_t* w1t  = (ushort_t*)alloc((size_t)HEADS * MAXW * HID * 2);
  ushort_t* w2t  = (ushort_t*)alloc((size_t)HEADS * HID * MAXW * 2);
  float*    G    = (float*)   alloc(256 * 256 * 4);
  float*    s    = (float*)   alloc(256 * 4);
  float*    As   = (float*)   alloc((size_t)HEADS * MAXW * 4);
  float*    Bs   = (float*)   alloc((size_t)HEADS * MAXW * 4);
  int*      flg  = (int*)     alloc(256);
  int*      deg  = (int*)     alloc((size_t)N_NODES * 4);
  int*      st   = (int*)     alloc((size_t)N_NODES * 4);
  int*      cur  = (int*)     alloc((size_t)N_NODES * 4);
  int*      eids = (int*)     alloc((size_t)E_EDGES * 4);
  ushort_t* hT   = (ushort_t*)alloc((size_t)HID * NT * 2);
  int*      bsum = (int*)     alloc(NB_SCAN * 4);

  hipLaunchKernelGGL(k_initdet,   dim3(512),         dim3(256), 0, stream, ei, G, s, deg, flg, hT);
  hipLaunchKernelGGL(k_hist,      dim3(2500),        dim3(256), 0, stream, ei, flg, deg);
  hipLaunchKernelGGL(k_scan1,     dim3(NB_SCAN),     dim3(256), 0, stream, deg, bsum);
  hipLaunchKernelGGL(k_scan3,     dim3(NB_SCAN),     dim3(256), 0, stream, deg, bsum, st, cur);
  hipLaunchKernelGGL(k_scatter,   dim3(2500),        dim3(256), 0, stream, ei, flg, cur, eids);
  hipLaunchKernelGGL(k_agg,       dim3(5000),        dim3(256), 0, stream, x, st, deg, eids, agg);
  hipLaunchKernelGGL(k_backbone,  dim3(625),         dim3(256), 0, stream, agg, Wb, bb, hbf, hT, s);
  hipLaunchKernelGGL(k_gram2,     dim3(40, 2),       dim3(256), 0, stream, hT, G);
  hipLaunchKernelGGL(k_transpose, dim3(128, 32, 2),  dim3(256), 0, stream, W1, W2, w1t, w2t);
  hipLaunchKernelGGL(k_stats,     dim3(8, 32),       dim3(256), 0, stream, G, s, w1t, b1, gamma, beta, As, Bs);
  hipLaunchKernelGGL(k_main,      dim3(79, 32),      dim3(512), 0, stream, hbf, w1t, w2t, As, Bs, b2, out);
}

// Round 14
// 805.729 us; speedup vs baseline: 1.0908x; 1.0908x over previous
//
#include <hip/hip_runtime.h>
#include <stdint.h>

#define N_NODES 20000
#define E_EDGES 640000
#define IN_DIM  128
#define HID     256
#define MAXW    512
#define HEADS   32
#define BN_EPS  1e-5f
#define NT      20480
#define NB_SCAN 79

typedef __attribute__((ext_vector_type(8))) short bf16x8;
typedef __attribute__((ext_vector_type(4))) float f32x4;
typedef __attribute__((ext_vector_type(16))) float f32x16;
typedef unsigned short ushort_t;

static __device__ __forceinline__ float bf2f(ushort_t u){
  union { unsigned int i; float f; } v; v.i = ((unsigned int)u) << 16; return v.f;
}
static __device__ __forceinline__ ushort_t f2bf(float f){
  union { float f; unsigned int i; } v; v.f = f;
  unsigned int r = v.i + 0x7fffu + ((v.i >> 16) & 1u);
  return (ushort_t)(r >> 16);
}

// ---------------- K0: init (zero G, s, deg, hT tail) + int64 layout detect ----------------
__global__ void k_initdet(const int* __restrict__ ei, float* __restrict__ G,
                          float* __restrict__ s, int* __restrict__ deg,
                          int* __restrict__ flag, ushort_t* __restrict__ hT){
  int i = blockIdx.x * blockDim.x + threadIdx.x;
  int stride = gridDim.x * blockDim.x;
  float4 z4 = make_float4(0.f, 0.f, 0.f, 0.f);
  float4* Gd = (float4*)G;
  for (int j = i; j < 256 * 256 / 4; j += stride) Gd[j] = z4;
  for (int j = i; j < N_NODES; j += stride) deg[j] = 0;
  if (i < 256) s[i] = 0.f;
  uint4 zi = make_uint4(0u, 0u, 0u, 0u);
  for (int j = i; j < 256 * 60; j += stride){
    int c = j / 60, o = (j % 60) * 8;
    *(uint4*)(hT + (size_t)c * NT + N_NODES + o) = zi;
  }
  if (blockIdx.x == 0){
    __shared__ int any_nz;
    if (threadIdx.x == 0) any_nz = 0;
    __syncthreads();
    int nz = 0;
    for (int k = threadIdx.x; k < 4096; k += blockDim.x)
      if (ei[2 * k + 1] != 0) nz = 1;
    if (nz) atomicOr(&any_nz, 1);
    __syncthreads();
    if (threadIdx.x == 0) flag[0] = (any_nz == 0) ? 1 : 0;   // 1 => int64 layout
  }
}

// ---------------- CSR build: histogram ----------------
__global__ __launch_bounds__(256) void k_hist(const int* __restrict__ ei,
                                              const int* __restrict__ flag,
                                              int* __restrict__ deg){
  int e = blockIdx.x * 256 + threadIdx.x;
  if (e >= E_EDGES) return;
  int src, dst;
  if (flag[0]){ src = ei[2 * e]; dst = ei[2 * E_EDGES + 2 * e]; }
  else        { src = ei[e];     dst = ei[E_EDGES + e]; }
  if ((unsigned)src >= N_NODES || (unsigned)dst >= N_NODES) return;
  atomicAdd(&deg[dst], 1);
}

// ---------------- parallel scan stage 1: per-block sums ----------------
__global__ __launch_bounds__(256) void k_scan1(const int* __restrict__ deg,
                                               int* __restrict__ bsum){
  __shared__ int ws[4];
  int b = blockIdx.x, t = threadIdx.x, i = b * 256 + t;
  int v = (i < N_NODES) ? deg[i] : 0;
  #pragma unroll
  for (int o = 32; o; o >>= 1) v += __shfl_down(v, o);
  if ((t & 63) == 0) ws[t >> 6] = v;
  __syncthreads();
  if (t == 0) bsum[b] = ws[0] + ws[1] + ws[2] + ws[3];
}

// ---------------- scan stage 2+3 fused: block-level exclusive scan ----------------
__global__ __launch_bounds__(256) void k_scan3(const int* __restrict__ deg,
                                               const int* __restrict__ bsum,
                                               int* __restrict__ start,
                                               int* __restrict__ cursor){
  __shared__ int a[2][256];
  __shared__ int base;
  int b = blockIdx.x, t = threadIdx.x, i = b * 256 + t;
  if (t == 0){
    int r = 0;
    for (int k = 0; k < b; k++) r += bsum[k];
    base = r;
  }
  int v = (i < N_NODES) ? deg[i] : 0;
  a[0][t] = v;
  __syncthreads();
  int pb = 0;
  for (int o = 1; o < 256; o <<= 1){
    int x = a[pb][t] + ((t >= o) ? a[pb][t - o] : 0);
    a[pb ^ 1][t] = x;
    __syncthreads();
    pb ^= 1;
  }
  if (i < N_NODES){
    int ex = base + a[pb][t] - v;
    start[i] = ex; cursor[i] = ex;
  }
}

// ---------------- CSR build: scatter edge sources ----------------
__global__ __launch_bounds__(256) void k_scatter(const int* __restrict__ ei,
                                                 const int* __restrict__ flag,
                                                 int* __restrict__ cursor,
                                                 int* __restrict__ eids){
  int e = blockIdx.x * 256 + threadIdx.x;
  if (e >= E_EDGES) return;
  int src, dst;
  if (flag[0]){ src = ei[2 * e]; dst = ei[2 * E_EDGES + 2 * e]; }
  else        { src = ei[e];     dst = ei[E_EDGES + e]; }
  if ((unsigned)src >= N_NODES || (unsigned)dst >= N_NODES) return;
  int p = atomicAdd(&cursor[dst], 1);
  eids[p] = src;
}

// ---------------- K-agg: agg[dst] = x[dst] + sum_{e in bucket} x[src_e] ----------------
__global__ __launch_bounds__(256) void k_agg(const float* __restrict__ x,
                                             const int* __restrict__ start,
                                             const int* __restrict__ deg,
                                             const int* __restrict__ eids,
                                             float* __restrict__ agg){
  int wid = (blockIdx.x * 256 + threadIdx.x) >> 6;
  int lane = threadIdx.x & 63;
  if (wid >= N_NODES) return;
  int s0 = start[wid], d = deg[wid];
  float2 acc = *(const float2*)(x + (size_t)wid * IN_DIM + 2 * lane);
  int i = 0;
  for (; i + 4 <= d; i += 4){
    int e0 = eids[s0+i], e1 = eids[s0+i+1], e2 = eids[s0+i+2], e3 = eids[s0+i+3];
    float2 v0 = *(const float2*)(x + (size_t)e0 * IN_DIM + 2 * lane);
    float2 v1 = *(const float2*)(x + (size_t)e1 * IN_DIM + 2 * lane);
    float2 v2 = *(const float2*)(x + (size_t)e2 * IN_DIM + 2 * lane);
    float2 v3 = *(const float2*)(x + (size_t)e3 * IN_DIM + 2 * lane);
    acc.x += (v0.x + v1.x) + (v2.x + v3.x);
    acc.y += (v0.y + v1.y) + (v2.y + v3.y);
  }
  for (; i < d; i++){
    int e0 = eids[s0+i];
    float2 v0 = *(const float2*)(x + (size_t)e0 * IN_DIM + 2 * lane);
    acc.x += v0.x; acc.y += v0.y;
  }
  *(float2*)(agg + (size_t)wid * IN_DIM + 2 * lane) = acc;
}

// ---------------- K2: h = relu(agg @ Wb + bb) -> hbf (row) + hT (col) + col-sums s ----------------
__global__ __launch_bounds__(256) void k_backbone(const float* __restrict__ agg,
                                                  const float* __restrict__ Wb,
                                                  const float* __restrict__ bb,
                                                  ushort_t* __restrict__ hbf,
                                                  ushort_t* __restrict__ hT,
                                                  float* __restrict__ s){
  __shared__ float WbS[32][256];
  __shared__ float aggS[32][36];
  int c = threadIdx.x;
  int n0 = blockIdx.x * 32;
  float acc[32];
  float bias = bb[c];
  #pragma unroll
  for (int i = 0; i < 32; i++) acc[i] = bias;
  for (int dc = 0; dc < 4; ++dc){
    __syncthreads();
    const float4* wsrc = (const float4*)(Wb + dc * 32 * 256);
    float4* wdst = (float4*)&WbS[0][0];
    #pragma unroll
    for (int i = 0; i < 8; i++) wdst[c + i * 256] = wsrc[c + i * 256];
    {
      int n = c >> 3, c4 = (c & 7) * 4;
      float4 v = *(const float4*)(agg + (size_t)(n0 + n) * IN_DIM + dc * 32 + c4);
      aggS[n][c4 + 0] = v.x; aggS[n][c4 + 1] = v.y;
      aggS[n][c4 + 2] = v.z; aggS[n][c4 + 3] = v.w;
    }
    __syncthreads();
    for (int d = 0; d < 32; ++d){
      float w = WbS[d][c];
      #pragma unroll
      for (int n = 0; n < 32; n++) acc[n] += aggS[n][d] * w;
    }
  }
  float ls = 0.f;
  ushort_t hrow[32];
  #pragma unroll
  for (int n = 0; n < 32; n++){
    float hv = acc[n] > 0.f ? acc[n] : 0.f;
    ushort_t hb = f2bf(hv);
    hbf[(size_t)(n0 + n) * HID + c] = hb;
    hrow[n] = hb;
    ls += bf2f(hb);
  }
  #pragma unroll
  for (int i = 0; i < 4; i++)
    *(uint4*)(hT + (size_t)c * NT + n0 + i * 8) = *(uint4*)(hrow + i * 8);
  unsafeAtomicAdd(&s[c], ls);
}

// ---------------- K-gram2: G += hT @ hT^T via 32x32x16 MFMA ----------------
__global__ __launch_bounds__(256) void k_gram2(const ushort_t* __restrict__ hT,
                                               float* __restrict__ G){
  const int t = threadIdx.x;
  const int w = t >> 6, l = t & 63;
  const int s = blockIdx.x, hh = blockIdx.y;
  const int wr = w >> 1, wc = w & 1;
  const int ca = hh * 128 + wr * 64;
  const int cb = wc * 128;
  const int l31 = l & 31, l5 = l >> 5;
  f32x16 acc[2][4];
  #pragma unroll
  for (int a = 0; a < 2; a++)
    #pragma unroll
    for (int b = 0; b < 4; b++)
      #pragma unroll
      for (int r = 0; r < 16; r++) acc[a][b][r] = 0.f;

  const size_t kb0 = (size_t)s * 512 + l5 * 8;
  for (int ks = 0; ks < 32; ks++){
    size_t k = kb0 + ks * 16;
    bf16x8 af[2], bfr[4];
    #pragma unroll
    for (int a = 0; a < 2; a++)
      af[a] = *(const bf16x8*)(hT + (size_t)(ca + a * 32 + l31) * NT + k);
    #pragma unroll
    for (int b = 0; b < 4; b++)
      bfr[b] = *(const bf16x8*)(hT + (size_t)(cb + b * 32 + l31) * NT + k);
    #pragma unroll
    for (int a = 0; a < 2; a++)
      #pragma unroll
      for (int b = 0; b < 4; b++)
        acc[a][b] = __builtin_amdgcn_mfma_f32_32x32x16_bf16(af[a], bfr[b], acc[a][b], 0, 0, 0);
  }
  #pragma unroll
  for (int a = 0; a < 2; a++)
    #pragma unroll
    for (int b = 0; b < 4; b++)
      #pragma unroll
      for (int r = 0; r < 16; r++){
        int grow = (r & 3) + 8 * (r >> 2) + 4 * l5;
        unsafeAtomicAdd(&G[(size_t)(ca + a * 32 + grow) * 256 + cb + b * 32 + l31], acc[a][b][r]);
      }
}

// ---------------- K5: transpose+convert, writing PRE-SWIZZLED LDS-image layouts ----------------
__global__ __launch_bounds__(256) void k_transpose(const float* __restrict__ W1,
                                                   const float* __restrict__ W2,
                                                   ushort_t* __restrict__ w1t,
                                                   ushort_t* __restrict__ w2t){
  __shared__ float tile[32][33];
  int which = blockIdx.z, h = blockIdx.y, b = blockIdx.x;
  const float* src; int R, C;
  if (which == 0){ src = W1 + (size_t)h * 256 * 512; R = 256; C = 512; }
  else           { src = W2 + (size_t)h * 512 * 256; R = 512; C = 256; }
  int tcn = C >> 5;
  int tr = b / tcn, tc = b % tcn;
  int r0 = tr * 32, c0 = tc * 32;
  int tx = threadIdx.x & 31, ty = threadIdx.x >> 5;
  #pragma unroll
  for (int i = 0; i < 32; i += 8) tile[ty + i][tx] = src[(size_t)(r0 + ty + i) * C + c0 + tx];
  __syncthreads();
  if (which == 0){
    ushort_t* dst = w1t + (size_t)h * 512 * 256;
    #pragma unroll
    for (int i = 0; i < 32; i += 8){
      int M = c0 + ty + i;
      int D = r0 + tx;
      int D2 = (((D >> 3) ^ (M & 7)) << 3) | (D & 7);
      dst[(size_t)M * 256 + D2] = f2bf(tile[tx][ty + i]);
    }
  } else {
    ushort_t* dst = w2t + (size_t)h * 256 * 512;
    #pragma unroll
    for (int i = 0; i < 32; i += 8){
      int dd = c0 + ty + i;
      int m  = r0 + tx;
      int g2 = ((m >> 3) & 3) ^ (dd & 3) ^ ((dd >> 2) & 3);
      size_t idx = (size_t)(m >> 5) * 8192 + dd * 32 + (g2 << 3) + (m & 7);
      dst[idx] = f2bf(tile[tx][ty + i]);
    }
  }
}

// ---------------- K4: BN stats (un-permutes w1t granules on load) ----------------
__global__ __launch_bounds__(256) void k_stats(const float* __restrict__ G,
                                               const float* __restrict__ s,
                                               const ushort_t* __restrict__ w1t,
                                               const float* __restrict__ b1,
                                               const float* __restrict__ gamma,
                                               const float* __restrict__ beta,
                                               float* __restrict__ As,
                                               float* __restrict__ Bs){
  __shared__ ushort_t wL[256][64];
  __shared__ float GL[16][256];
  __shared__ float sL[256];
  __shared__ float red[4][64];
  int h = blockIdx.y, m0 = blockIdx.x * 64;
  int t = threadIdx.x, m = t & 63, q = t >> 6;
  {
    int mm = t >> 2, part = t & 3;
    int Mrow = m0 + mm;
    const ushort_t* srcr = w1t + ((size_t)h * 512 + Mrow) * 256;
    #pragma unroll
    for (int k4 = 0; k4 < 16; ++k4){
      int kb = part * 64 + k4 * 4;
      int eo = (((kb >> 3) ^ (Mrow & 7)) << 3) | (kb & 7);
      ushort4 v = *(const ushort4*)(srcr + eo);
      wL[kb+0][mm]=v.x; wL[kb+1][mm]=v.y; wL[kb+2][mm]=v.z; wL[kb+3][mm]=v.w;
    }
  }
  sL[t & 255] = s[t & 255];
  float quad = 0.f;
  for (int dc = 0; dc < 16; ++dc){
    __syncthreads();
    const float4* gs = (const float4*)(G + (size_t)dc * 16 * 256);
    float4* gd = (float4*)&GL[0][0];
    #pragma unroll
    for (int i = 0; i < 4; i++) gd[t + i * 256] = gs[t + i * 256];
    __syncthreads();
    #pragma unroll
    for (int i = 0; i < 4; i++){
      int dl = q * 4 + i;
      float wd = bf2f(wL[dc * 16 + dl][m]);
      float u = 0.f;
      for (int k = 0; k < 256; ++k) u += GL[dl][k] * bf2f(wL[k][m]);
      quad += wd * u;
    }
  }
  red[q][m] = quad;
  __syncthreads();
  if (q == 0){
    float qd = red[0][m] + red[1][m] + red[2][m] + red[3][m];
    float dot_s = 0.f;
    for (int k = 0; k < 256; ++k) dot_s += sL[k] * bf2f(wL[k][m]);
    float b1v = b1[(size_t)h * 512 + m0 + m];
    float invN = 1.f / (float)N_NODES;
    float mean = dot_s * invN + b1v;
    float ez2 = (qd + 2.f * b1v * dot_s) * invN + b1v * b1v;
    float var = ez2 - mean * mean;
    float rstd = rsqrtf(var + BN_EPS);
    float gv = gamma[(size_t)h * 512 + m0 + m];
    float be = beta[(size_t)h * 512 + m0 + m];
    float Av = rstd * gv;
    As[(size_t)h * 512 + m0 + m] = Av;
    Bs[(size_t)h * 512 + m0 + m] = be - mean * Av;
  }
}

// ---------------- K6 v14: DMA staging + parity-interleaved conflict-free LDS handoff ----------------
// asw row (per node, 80B stride): position s(m) = (m&15)*2 + (m>>4). Writer: 16B/thread
// contiguous. Reader: 2x b128 (half-broadcast) + v_perm parity extract. No bpermute.
__global__ __launch_bounds__(512, 2) void k_main(const ushort_t* __restrict__ hbf,
                                                 const ushort_t* __restrict__ w1t,
                                                 const ushort_t* __restrict__ w2t,
                                                 const float* __restrict__ As,
                                                 const float* __restrict__ Bs,
                                                 const float* __restrict__ b2,
                                                 float* __restrict__ out){
  __shared__ __align__(16) char lds_all[86016];   // [0,64K): 2x(w1 16K|w2 16K); [64K,+20K): 8 x 2560B asw
  const int h = blockIdx.y;
  const int n0 = blockIdx.x * 256;
  const int t = threadIdx.x;
  const int w = t >> 6, l = t & 63;
  const int l15 = l & 15, l4 = l >> 4;
  const int nw = n0 + w * 32;
  const f32x4 fzero = {0.f, 0.f, 0.f, 0.f};
  const bf16x8 bzero = {0,0,0,0,0,0,0,0};
  char* asw = lds_all + 65536 + w * 2560;   // wave-private 32 rows x 80B

  bf16x8 afr[2][8];
  #pragma unroll
  for (int nset = 0; nset < 2; nset++){
    int row = nw + nset * 16 + l15;
    const ushort_t* p = hbf + (size_t)row * HID + l4 * 8;
    #pragma unroll
    for (int kk = 0; kk < 8; kk++){
      bf16x8 v = bzero;
      if (row < N_NODES) v = *(const bf16x8*)(p + kk * 32);
      afr[nset][kk] = v;
    }
  }
  f32x4 oacc[16][2];
  #pragma unroll
  for (int i = 0; i < 16; i++){ oacc[i][0] = fzero; oacc[i][1] = fzero; }

  const float* Asp = As + (size_t)h * 512;
  const float* Bsp = Bs + (size_t)h * 512;
  const char* w1g = (const char*)(w1t + (size_t)h * 512 * 256);
  const char* w2g = (const char*)(w2t + (size_t)h * 256 * 512);
  const int woff = w * 2048 + l * 16;

  // prologue: DMA chunk 0 -> buffer 0
  {
    __builtin_amdgcn_global_load_lds((const __attribute__((address_space(1))) void*)(w1g + woff),
                                     (__attribute__((address_space(3))) void*)(lds_all + w * 2048), 16, 0, 0);
    __builtin_amdgcn_global_load_lds((const __attribute__((address_space(1))) void*)(w1g + woff + 1024),
                                     (__attribute__((address_space(3))) void*)(lds_all + w * 2048 + 1024), 16, 0, 0);
    __builtin_amdgcn_global_load_lds((const __attribute__((address_space(1))) void*)(w2g + woff),
                                     (__attribute__((address_space(3))) void*)(lds_all + 16384 + w * 2048), 16, 0, 0);
    __builtin_amdgcn_global_load_lds((const __attribute__((address_space(1))) void*)(w2g + woff + 1024),
                                     (__attribute__((address_space(3))) void*)(lds_all + 16384 + w * 2048 + 1024), 16, 0, 0);
  }
  __syncthreads();

  const int win = (l4 & 1) * 32;                       // 32B window within asw row
  const unsigned sel = (l4 >> 1) ? 0x07060302u : 0x05040100u;   // parity extract selector

  for (int c = 0; c < 16; ++c){
    const int cur = c & 1;
    const int mc0 = c * 32;
    const bool pf = (c < 15);
    if (pf){
      const int nb = (c + 1) * 16384;
      char* db = lds_all + (cur ^ 1) * 32768;
      __builtin_amdgcn_global_load_lds((const __attribute__((address_space(1))) void*)(w1g + nb + woff),
                                       (__attribute__((address_space(3))) void*)(db + w * 2048), 16, 0, 0);
      __builtin_amdgcn_global_load_lds((const __attribute__((address_space(1))) void*)(w1g + nb + woff + 1024),
                                       (__attribute__((address_space(3))) void*)(db + w * 2048 + 1024), 16, 0, 0);
      __builtin_amdgcn_global_load_lds((const __attribute__((address_space(1))) void*)(w2g + nb + woff),
                                       (__attribute__((address_space(3))) void*)(db + 16384 + w * 2048), 16, 0, 0);
      __builtin_amdgcn_global_load_lds((const __attribute__((address_space(1))) void*)(w2g + nb + woff + 1024),
                                       (__attribute__((address_space(3))) void*)(db + 16384 + w * 2048 + 1024), 16, 0, 0);
    }
    const char* w1b = lds_all + cur * 32768;
    const char* w2b = lds_all + cur * 32768 + 16384;

    // ---- GEMM1 (swapped): zt[nset][ct]
    f32x4 zt[2][2];
    zt[0][0] = fzero; zt[0][1] = fzero; zt[1][0] = fzero; zt[1][1] = fzero;
    __builtin_amdgcn_s_setprio(1);
    #pragma unroll
    for (int kk = 0; kk < 8; kk++){
      #pragma unroll
      for (int ct = 0; ct < 2; ct++){
        int r1 = ct * 16 + l15;
        int gr = kk * 4 + l4;
        bf16x8 wf = *(const bf16x8*)(w1b + r1 * 512 + ((gr ^ (r1 & 7)) * 16));
        zt[0][ct] = __builtin_amdgcn_mfma_f32_16x16x32_bf16(wf, afr[0][kk], zt[0][ct], 0, 0, 0);
        zt[1][ct] = __builtin_amdgcn_mfma_f32_16x16x32_bf16(wf, afr[1][kk], zt[1][ct], 0, 0, 0);
      }
    }
    __builtin_amdgcn_s_setprio(0);

    // ---- BN fold + ReLU + parity-interleaved pack -> asw (16B/thread, conflict-free)
    {
      float4 Av0 = *(const float4*)(Asp + mc0 + l4 * 4);
      float4 Bv0 = *(const float4*)(Bsp + mc0 + l4 * 4);
      float4 Av1 = *(const float4*)(Asp + mc0 + 16 + l4 * 4);
      float4 Bv1 = *(const float4*)(Bsp + mc0 + 16 + l4 * 4);
      #pragma unroll
      for (int nset = 0; nset < 2; nset++){
        float c00 = zt[nset][0][0] * Av0.x + Bv0.x; c00 = c00 > 0.f ? c00 : 0.f;
        float c01 = zt[nset][0][1] * Av0.y + Bv0.y; c01 = c01 > 0.f ? c01 : 0.f;
        float c02 = zt[nset][0][2] * Av0.z + Bv0.z; c02 = c02 > 0.f ? c02 : 0.f;
        float c03 = zt[nset][0][3] * Av0.w + Bv0.w; c03 = c03 > 0.f ? c03 : 0.f;
        float c10 = zt[nset][1][0] * Av1.x + Bv1.x; c10 = c10 > 0.f ? c10 : 0.f;
        float c11 = zt[nset][1][1] * Av1.y + Bv1.y; c11 = c11 > 0.f ? c11 : 0.f;
        float c12 = zt[nset][1][2] * Av1.z + Bv1.z; c12 = c12 > 0.f ? c12 : 0.f;
        float c13 = zt[nset][1][3] * Av1.w + Bv1.w; c13 = c13 > 0.f ? c13 : 0.f;
        uint4 pk;
        pk.x = (unsigned)f2bf(c00) | ((unsigned)f2bf(c10) << 16);   // s=8*l4+0,1 (r0: ct0,ct1)
        pk.y = (unsigned)f2bf(c01) | ((unsigned)f2bf(c11) << 16);   // r1
        pk.z = (unsigned)f2bf(c02) | ((unsigned)f2bf(c12) << 16);   // r2
        pk.w = (unsigned)f2bf(c03) | ((unsigned)f2bf(c13) << 16);   // r3
        *(uint4*)(asw + (nset * 16 + l15) * 80 + l4 * 16) = pk;
      }
    }
    // ---- read back: m-octet l4 = parity (l4>>1) slots of window (l4&1)*32
    bf16x8 aa[2];
    #pragma unroll
    for (int nset = 0; nset < 2; nset++){
      const char* rp = asw + (nset * 16 + l15) * 80 + win;
      uint4 wa = *(const uint4*)(rp);
      uint4 wb = *(const uint4*)(rp + 16);
      unsigned o0 = __builtin_amdgcn_perm(wa.y, wa.x, sel);
      unsigned o1 = __builtin_amdgcn_perm(wa.w, wa.z, sel);
      unsigned o2 = __builtin_amdgcn_perm(wb.y, wb.x, sel);
      unsigned o3 = __builtin_amdgcn_perm(wb.w, wb.z, sel);
      uint4 q = make_uint4(o0, o1, o2, o3);
      aa[nset] = *(bf16x8*)&q;
    }

    // ---- GEMM2 (swapped)
    __builtin_amdgcn_s_setprio(1);
    #pragma unroll
    for (int ddt = 0; ddt < 16; ddt++){
      int dd = ddt * 16 + l15;
      int g2 = l4 ^ (dd & 3) ^ ((dd >> 2) & 3);
      bf16x8 wf2 = *(const bf16x8*)(w2b + dd * 64 + g2 * 16);
      oacc[ddt][0] = __builtin_amdgcn_mfma_f32_16x16x32_bf16(wf2, aa[0], oacc[ddt][0], 0, 0, 0);
      oacc[ddt][1] = __builtin_amdgcn_mfma_f32_16x16x32_bf16(wf2, aa[1], oacc[ddt][1], 0, 0, 0);
    }
    __builtin_amdgcn_s_setprio(0);

    __syncthreads();   // drains DMA (vmcnt) + orders buffer reuse
  }

  // ---- epilogue: per-wave 8KB LDS slice, transpose to coalesced 512B row stores
  char* slice = lds_all + w * 8192;
  const int gsl = l & 31;
  const int rhalf = l >> 5;
  #pragma unroll
  for (int nset = 0; nset < 2; nset++){
    #pragma unroll
    for (int half = 0; half < 2; half++){
      #pragma unroll
      for (int dq = 0; dq < 8; dq++){
        int ddt = half * 8 + dq;
        *(f32x4*)(slice + l15 * 512 + (((dq * 4 + l4) ^ (l15 & 7)) * 16)) = oacc[ddt][nset];
      }
      float4 b2v = *(const float4*)(b2 + (size_t)h * 256 + half * 128 + gsl * 4);
      #pragma unroll
      for (int j = 0; j < 8; j++){
        int rr = rhalf + j * 2;
        f32x4 v = *(const f32x4*)(slice + rr * 512 + ((gsl ^ (rr & 7)) * 16));
        int n = nw + nset * 16 + rr;
        if (n < N_NODES){
          float4 o;
          o.x = v[0] + b2v.x; o.y = v[1] + b2v.y;
          o.z = v[2] + b2v.z; o.w = v[3] + b2v.w;
          *(float4*)(out + (size_t)n * (HEADS * HID) + h * HID + half * 128 + gsl * 4) = o;
        }
      }
    }
  }
}

extern "C" void kernel_launch(void* const* d_in, const int* in_sizes, int n_in,
                              void* d_out, int out_size, void* d_ws, size_t ws_size,
                              hipStream_t stream){
  const float* x     = (const float*)d_in[0];
  const int*   ei    = (const int*)  d_in[1];
  const float* Wb    = (const float*)d_in[2];
  const float* bb    = (const float*)d_in[3];
  const float* W1    = (const float*)d_in[4];
  const float* b1    = (const float*)d_in[5];
  const float* gamma = (const float*)d_in[6];
  const float* beta  = (const float*)d_in[7];
  const float* W2    = (const float*)d_in[8];
  const float* b2    = (const float*)d_in[9];
  float* out = (float*)d_out;

  char* ws = (char*)d_ws;
  size_t off = 0;
  auto alloc = [&](size_t bytes){ void* p = ws + off; off += (bytes + 255) & ~(size_t)255; return p; };
  float*    agg  = (float*)   alloc((size_t)N_NODES * IN_DIM * 4);
  ushort_t* hbf  = (ushort_t*)alloc((size_t)N_NODES * HID * 2);
  ushort_t* w1t  = (ushort_t*)alloc((size_t)HEADS * MAXW * HID * 2);
  ushort_t* w2t  = (ushort_t*)alloc((size_t)HEADS * HID * MAXW * 2);
  float*    G    = (float*)   alloc(256 * 256 * 4);
  float*    s    = (float*)   alloc(256 * 4);
  float*    As   = (float*)   alloc((size_t)HEADS * MAXW * 4);
  float*    Bs   = (float*)   alloc((size_t)HEADS * MAXW * 4);
  int*      flg  = (int*)     alloc(256);
  int*      deg  = (int*)     alloc((size_t)N_NODES * 4);
  int*      st   = (int*)     alloc((size_t)N_NODES * 4);
  int*      cur  = (int*)     alloc((size_t)N_NODES * 4);
  int*      eids = (int*)     alloc((size_t)E_EDGES * 4);
  ushort_t* hT   = (ushort_t*)alloc((size_t)HID * NT * 2);
  int*      bsum = (int*)     alloc(NB_SCAN * 4);

  hipLaunchKernelGGL(k_initdet,   dim3(512),         dim3(256), 0, stream, ei, G, s, deg, flg, hT);
  hipLaunchKernelGGL(k_hist,      dim3(2500),        dim3(256), 0, stream, ei, flg, deg);
  hipLaunchKernelGGL(k_scan1,     dim3(NB_SCAN),     dim3(256), 0, stream, deg, bsum);
  hipLaunchKernelGGL(k_scan3,     dim3(NB_SCAN),     dim3(256), 0, stream, deg, bsum, st, cur);
  hipLaunchKernelGGL(k_scatter,   dim3(2500),        dim3(256), 0, stream, ei, flg, cur, eids);
  hipLaunchKernelGGL(k_agg,       dim3(5000),        dim3(256), 0, stream, x, st, deg, eids, agg);
  hipLaunchKernelGGL(k_backbone,  dim3(625),         dim3(256), 0, stream, agg, Wb, bb, hbf, hT, s);
  hipLaunchKernelGGL(k_gram2,     dim3(40, 2),       dim3(256), 0, stream, hT, G);
  hipLaunchKernelGGL(k_transpose, dim3(128, 32, 2),  dim3(256), 0, stream, W1, W2, w1t, w2t);
  hipLaunchKernelGGL(k_stats,     dim3(8, 32),       dim3(256), 0, stream, G, s, w1t, b1, gamma, beta, As, Bs);
  hipLaunchKernelGGL(k_main,      dim3(79, 32),      dim3(512), 0, stream, hbf, w1t, w2t, As, Bs, b2, out);
}